// Round 7
// baseline (2652.811 us; speedup 1.0000x reference)
//
#include <hip/hip_runtime.h>
#include <hip/hip_bf16.h>
#include <stdint.h>

#define D_MODEL 2048
#define D_FFN   8192
#define NTOK    8192
#define TOPK    256

typedef __bf16 bf16x8 __attribute__((ext_vector_type(8)));
typedef __bf16 bf16x4 __attribute__((ext_vector_type(4)));
typedef float  f32x4  __attribute__((ext_vector_type(4)));

// ---------------------------------------------------------------------------
// global -> LDS direct (16B per lane; LDS dest = wave-uniform base + lane*16)
// ---------------------------------------------------------------------------
__device__ inline void load_lds16(const void* g, void* l) {
    __builtin_amdgcn_global_load_lds((__attribute__((address_space(1))) void*)g,
                                     (__attribute__((address_space(3))) void*)l,
                                     16, 0, 0);
}

// ===========================================================================
// 256x256 bf16 GEMM, m201-style 4-phase-per-K-tile cadence (8 waves, BK=64,
// dbuf LDS, per-phase {issue reads -> barrier -> lgkm(0) -> 16 MFMA -> barrier}).
// C[M,N] fp32 = sum_seg A_seg[M,segK] * B_seg[N,segK]^T. grid=(N/256, M/256).
//
// Register budget (r4/r5 post-mortem): amdgpu_waves_per_eu(2) => 256 regs/wave
// (acc[8][4] lives in AGPRs; ~100 arch VGPRs). Without it the backend caps at
// 128 and spills 3.8 GB/dispatch.
// Safety invariants (hand-checked):
//  - STAGE(t+1 -> buf[b^1]) issued in P1 of K-tile t: buf[b^1]'s reads (tile
//    t-1) were lgkm(0)-drained by every wave before K-tile t-1's closing
//    barrier.
//  - Reads of tile t+1 begin only after P4's vmcnt(0) + barrier (stage landed,
//    all waves).
// ===========================================================================
#define MFMA_Q(AF, MLO) do {                                                   \
    _Pragma("unroll") for (int mi = 0; mi < 4; ++mi)                           \
    _Pragma("unroll") for (int ni = 0; ni < 4; ++ni)                           \
        acc[(MLO) + mi][ni] = __builtin_amdgcn_mfma_f32_16x16x32_bf16(         \
            AF[mi], bfr[ni], acc[(MLO) + mi][ni], 0, 0, 0);                    \
} while (0)

#define PHASE_TAIL()                                                           \
    asm volatile("s_waitcnt lgkmcnt(0)" ::: "memory");                         \
    __builtin_amdgcn_sched_barrier(0)

template<int NSEG>
__global__ __attribute__((amdgpu_flat_work_group_size(512, 512),
                          amdgpu_waves_per_eu(2)))
void g256(const __bf16* __restrict__ A0, const __bf16* __restrict__ A1,
          const __bf16* __restrict__ A2,
          const __bf16* __restrict__ B0, const __bf16* __restrict__ B1,
          const __bf16* __restrict__ B2,
          float* __restrict__ C, int segK, int ldc)
{
    __shared__ __align__(16) __bf16 sA[2][256][64];   // 64 KiB
    __shared__ __align__(16) __bf16 sB[2][256][64];   // 64 KiB

    const int tid  = threadIdx.x;
    const int lane = tid & 63;
    const int wid  = tid >> 6;          // 0..7
    const int mb   = blockIdx.y;
    const int nb   = blockIdx.x;

    const int wm  = (wid >> 2) * 128;   // wave rows [wm, wm+128)
    const int wn  = (wid & 3) * 64;     // wave cols [wn, wn+64)
    const int fr  = lane & 15;
    const int fr7 = fr & 7;
    const int q   = lane >> 4;          // 0..3

    f32x4 acc[8][4] = {};

    // staging: thread covers row (tid>>3); global source chunk pre-swizzled
    // so LDS stays linear (rule 21: same XOR on source and read)
    const int scol = (((tid & 7) ^ ((tid >> 3) & 7)) << 3);  // element offset

    const int NKT = (NSEG * segK) / 64;

    auto STAGE = [&](int kt, int b) {
        const int kg = kt * 64;
        int seg = 0, kin = kg;
        if (NSEG > 1) { seg = kg / segK; kin = kg - seg * segK; }
        const __bf16* Aseg = (NSEG == 1 || seg == 0) ? A0 : (seg == 1 ? A1 : A2);
        const __bf16* Bseg = (NSEG == 1 || seg == 0) ? B0 : (seg == 1 ? B1 : B2);
        const __bf16* ga = Aseg + (size_t)(mb * 256 + (tid >> 3)) * segK + kin + scol;
        const __bf16* gb = Bseg + (size_t)(nb * 256 + (tid >> 3)) * segK + kin + scol;
        const size_t rstep = (size_t)64 * segK;
        #pragma unroll
        for (int i = 0; i < 4; ++i) {
            load_lds16(ga + i * rstep, &sA[b][i * 64 + wid * 8][0]);
            load_lds16(gb + i * rstep, &sB[b][i * 64 + wid * 8][0]);
        }
    };

    // prologue: tile 0 staged and landed before first reads
    STAGE(0, 0);
    asm volatile("s_waitcnt vmcnt(0)" ::: "memory");
    __builtin_amdgcn_s_barrier();

    for (int t = 0; t < NKT; ++t) {
        const int b = t & 1;
        bf16x8 bfr[4], afA[4], afB[4];
        const int ce0 = ((0 + q) ^ fr7) * 8;   // kk=0 swizzled element offset
        const int ce1 = ((4 + q) ^ fr7) * 8;   // kk=1

        // ---- P1: bfr0 + afA0 reads; stage next tile; 16 MFMA (m 0-63, kk0) ----
        #pragma unroll
        for (int ni = 0; ni < 4; ++ni)
            bfr[ni] = *(const bf16x8*)&sB[b][wn + fr + ni * 16][ce0];
        #pragma unroll
        for (int mi = 0; mi < 4; ++mi)
            afA[mi] = *(const bf16x8*)&sA[b][wm + fr + mi * 16][ce0];
        if (t + 1 < NKT) STAGE(t + 1, b ^ 1);
        __builtin_amdgcn_s_barrier();
        PHASE_TAIL();
        __builtin_amdgcn_s_setprio(1);
        MFMA_Q(afA, 0);
        __builtin_amdgcn_s_setprio(0);
        __builtin_amdgcn_s_barrier();

        // ---- P2: afB0 reads; 16 MFMA (m 64-127, kk0) ----
        #pragma unroll
        for (int mi = 0; mi < 4; ++mi)
            afB[mi] = *(const bf16x8*)&sA[b][wm + 64 + fr + mi * 16][ce0];
        __builtin_amdgcn_s_barrier();
        PHASE_TAIL();
        __builtin_amdgcn_s_setprio(1);
        MFMA_Q(afB, 4);
        __builtin_amdgcn_s_setprio(0);
        __builtin_amdgcn_s_barrier();

        // ---- P3: bfr1 + afA1 reads; 16 MFMA (m 0-63, kk1) ----
        #pragma unroll
        for (int ni = 0; ni < 4; ++ni)
            bfr[ni] = *(const bf16x8*)&sB[b][wn + fr + ni * 16][ce1];
        #pragma unroll
        for (int mi = 0; mi < 4; ++mi)
            afA[mi] = *(const bf16x8*)&sA[b][wm + fr + mi * 16][ce1];
        __builtin_amdgcn_s_barrier();
        PHASE_TAIL();
        __builtin_amdgcn_s_setprio(1);
        MFMA_Q(afA, 0);
        __builtin_amdgcn_s_setprio(0);
        __builtin_amdgcn_s_barrier();

        // ---- P4: afB1 reads; 16 MFMA (m 64-127, kk1); vmcnt drain ----
        #pragma unroll
        for (int mi = 0; mi < 4; ++mi)
            afB[mi] = *(const bf16x8*)&sA[b][wm + 64 + fr + mi * 16][ce1];
        __builtin_amdgcn_s_barrier();
        PHASE_TAIL();
        __builtin_amdgcn_s_setprio(1);
        MFMA_Q(afB, 4);
        __builtin_amdgcn_s_setprio(0);
        asm volatile("s_waitcnt vmcnt(0)" ::: "memory");  // next tile landed
        __builtin_amdgcn_s_barrier();
    }

    // epilogue: C/D layout col = lane&15, row = (lane>>4)*4 + reg
    const int orow = q * 4;
    #pragma unroll
    for (int mi = 0; mi < 8; ++mi)
        #pragma unroll
        for (int ni = 0; ni < 4; ++ni)
            #pragma unroll
            for (int j = 0; j < 4; ++j) {
                const int r = mb * 256 + wm + mi * 16 + orow + j;
                const int c = nb * 256 + wn + ni * 16 + fr;
                C[(size_t)r * ldc + c] = acc[mi][ni][j];
            }
}

// ---------------------------------------------------------------------------
// legacy 128x128 bf16 GEMM (m97 structure) — used for the down projection
// ---------------------------------------------------------------------------
template<int NSEG>
__global__ __launch_bounds__(256)
void gemm_bt(const __bf16* __restrict__ A0, const __bf16* __restrict__ A1,
             const __bf16* __restrict__ A2,
             const __bf16* __restrict__ B0, const __bf16* __restrict__ B1,
             const __bf16* __restrict__ B2,
             float* __restrict__ C, int segK, int ldc)
{
    __shared__ __align__(16) __bf16 sA[128][64];
    __shared__ __align__(16) __bf16 sB[128][64];

    const int tid  = threadIdx.x;
    const int lane = tid & 63;
    const int wid  = tid >> 6;
    const int mb   = blockIdx.y;
    const int nb   = blockIdx.x;

    f32x4 acc[4][4] = {};

    const int stR = wid * 8 + (lane >> 3);
    const int stC = (lane & 7) * 8;
    const int NKT = (NSEG * segK) / 64;

    for (int kt = 0; kt < NKT; ++kt) {
        const int kg  = kt * 64;
        const int seg = kg / segK;
        const int kin = kg - seg * segK;
        const __bf16* Aseg = (NSEG == 1 || seg == 0) ? A0 : (seg == 1 ? A1 : A2);
        const __bf16* Bseg = (NSEG == 1 || seg == 0) ? B0 : (seg == 1 ? B1 : B2);

        #pragma unroll
        for (int i = 0; i < 4; ++i) {
            const __bf16* gA = Aseg + (size_t)(mb * 128 + i * 32 + stR) * segK + (kin + stC);
            const __bf16* gB = Bseg + (size_t)(nb * 128 + i * 32 + stR) * segK + (kin + stC);
            load_lds16(gA, &sA[i * 32 + wid * 8][0]);
            load_lds16(gB, &sB[i * 32 + wid * 8][0]);
        }
        __syncthreads();

        const int wm = (wid >> 1) * 64;
        const int wn = (wid & 1) * 64;
        const int fr = lane & 15;
        const int fk = (lane >> 4) * 8;
        #pragma unroll
        for (int kk = 0; kk < 2; ++kk) {
            bf16x8 af[4], bfr[4];
            #pragma unroll
            for (int mi = 0; mi < 4; ++mi)
                af[mi] = *(const bf16x8*)&sA[wm + mi * 16 + fr][kk * 32 + fk];
            #pragma unroll
            for (int ni = 0; ni < 4; ++ni)
                bfr[ni] = *(const bf16x8*)&sB[wn + ni * 16 + fr][kk * 32 + fk];
            #pragma unroll
            for (int mi = 0; mi < 4; ++mi)
                #pragma unroll
                for (int ni = 0; ni < 4; ++ni)
                    acc[mi][ni] = __builtin_amdgcn_mfma_f32_16x16x32_bf16(
                        af[mi], bfr[ni], acc[mi][ni], 0, 0, 0);
        }
        __syncthreads();
    }

    const int wm = (wid >> 1) * 64;
    const int wn = (wid & 1) * 64;
    const int orow = (lane >> 4) * 4;
    const int ocol = lane & 15;
    #pragma unroll
    for (int mi = 0; mi < 4; ++mi)
        #pragma unroll
        for (int ni = 0; ni < 4; ++ni)
            #pragma unroll
            for (int j = 0; j < 4; ++j) {
                const int r = mb * 128 + wm + mi * 16 + orow + j;
                const int c = nb * 128 + wn + ni * 16 + ocol;
                C[(size_t)r * ldc + c] = acc[mi][ni][j];
            }
}

// ---------------------------------------------------------------------------
__global__ __launch_bounds__(256)
void split_convert(const float* __restrict__ in, __bf16* __restrict__ hi,
                   __bf16* __restrict__ lo, int n4)
{
    const int i = blockIdx.x * 256 + threadIdx.x;
    if (i >= n4) return;
    const float4 v = ((const float4*)in)[i];
    float f[4] = {v.x, v.y, v.z, v.w};
    bf16x4 h, l;
    #pragma unroll
    for (int j = 0; j < 4; ++j) {
        __bf16 hb = (__bf16)f[j];
        h[j] = hb;
        l[j] = (__bf16)(f[j] - (float)hb);
    }
    ((bf16x4*)hi)[i] = h;
    ((bf16x4*)lo)[i] = l;
}

// ---------------------------------------------------------------------------
template<bool SPLIT>
__global__ __launch_bounds__(256)
void transpose_bf16(const float* __restrict__ in, __bf16* __restrict__ outHi,
                    __bf16* __restrict__ outLo, int R, int C)
{
    __shared__ float tile[32][33];
    const int bx = blockIdx.x * 32;
    const int by = blockIdx.y * 32;
    const int tx = threadIdx.x & 31;
    const int ty = threadIdx.x >> 5;
    #pragma unroll
    for (int i = 0; i < 4; ++i)
        tile[ty + 8 * i][tx] = in[(size_t)(by + ty + 8 * i) * C + (bx + tx)];
    __syncthreads();
    #pragma unroll
    for (int i = 0; i < 4; ++i) {
        const float v = tile[tx][ty + 8 * i];
        const size_t o = (size_t)(bx + ty + 8 * i) * R + (by + tx);
        const __bf16 h = (__bf16)v;
        outHi[o] = h;
        if (SPLIT) outLo[o] = (__bf16)(v - (float)h);
    }
}

// ---------------------------------------------------------------------------
// exact top-256 per row of G[rows][D_FFN] fp32 (G computed to ~1e-6):
// radix-select pivot, then fp64-exact arbitration of the ambiguous boundary.
// ---------------------------------------------------------------------------
#define TK_EPS 3e-5f
#define TK_MAXA 64

__global__ __launch_bounds__(256)
void topk256(const float* __restrict__ G, const float* __restrict__ xblk,
             const float* __restrict__ wgate,
             int* __restrict__ idxOut, float* __restrict__ gkOut)
{
    const int row = blockIdx.x;
    const int t = threadIdx.x;
    const int lane = t & 63;
    const int wid  = t >> 6;

    __shared__ unsigned keys[D_FFN];
    __shared__ float    xr[D_MODEL];
    __shared__ unsigned hist[256];
    __shared__ unsigned scanb[256];
    __shared__ int      sIdx[TOPK];
    __shared__ float    sVal[TOPK];
    __shared__ int      ambIdx[TK_MAXA];
    __shared__ double   ambVal[TK_MAXA];
    __shared__ double   redW[4];
    __shared__ unsigned sh_bin, sh_above, sh_nc, sh_na, sh_fill;

    const float* g = G + (size_t)row * D_FFN;
    const float* xrow = xblk + (size_t)row * D_MODEL;
    for (int i = t; i < D_FFN; i += 256) {
        const unsigned u = __float_as_uint(g[i]);
        keys[i] = (u & 0x80000000u) ? ~u : (u | 0x80000000u);
    }
    for (int i = t; i < D_MODEL; i += 256) xr[i] = xrow[i];
    if (t == 0) { sh_nc = 0; sh_na = 0; sh_fill = 0; }
    __syncthreads();

    unsigned prefix = 0, pmask = 0;
    int remaining = TOPK;
    for (int shift = 24; shift >= 0; shift -= 8) {
        hist[t] = 0;
        __syncthreads();
        for (int i = t; i < D_FFN; i += 256) {
            const unsigned k = keys[i];
            if ((k & pmask) == prefix) atomicAdd(&hist[(k >> shift) & 255u], 1u);
        }
        __syncthreads();
        scanb[t] = hist[t];
        __syncthreads();
        for (int off = 1; off < 256; off <<= 1) {
            const unsigned add = (t + off < 256) ? scanb[t + off] : 0u;
            __syncthreads();
            scanb[t] += add;
            __syncthreads();
        }
        const unsigned above = (t == 255) ? 0u : scanb[t + 1];
        if (scanb[t] >= (unsigned)remaining && above < (unsigned)remaining) {
            sh_bin = (unsigned)t;
            sh_above = above;
        }
        __syncthreads();
        prefix |= sh_bin << shift;
        pmask  |= 0xFFu << shift;
        remaining -= (int)sh_above;
        __syncthreads();
    }
    const unsigned Tkey = prefix;
    const float vT = __uint_as_float((Tkey & 0x80000000u) ? (Tkey & 0x7FFFFFFFu) : ~Tkey);

    for (int i = t; i < D_FFN; i += 256) {
        const unsigned k = keys[i];
        const float f = __uint_as_float((k & 0x80000000u) ? (k & 0x7FFFFFFFu) : ~k);
        if (f > vT + TK_EPS) {
            const unsigned p = atomicAdd(&sh_nc, 1u);
            sIdx[p] = i;
            sVal[p] = f;
        } else if (f >= vT - TK_EPS) {
            const unsigned p = atomicAdd(&sh_na, 1u);
            if (p < TK_MAXA) ambIdx[p] = i;
        }
    }
    __syncthreads();
    const int nc = (int)sh_nc;
    const int na = min((int)sh_na, TK_MAXA);
    const int need = TOPK - nc;

    if (need >= na) {
        if (t < na) {
            const unsigned k = keys[ambIdx[t]];
            sIdx[nc + t] = ambIdx[t];
            sVal[nc + t] = __uint_as_float((k & 0x80000000u) ? (k & 0x7FFFFFFFu) : ~k);
        }
        __syncthreads();
    } else {
        for (int j = 0; j < na; ++j) {
            const int col = ambIdx[j];
            double p = 0.0;
            for (int k = t; k < D_MODEL; k += 256)
                p += (double)xr[k] * (double)wgate[(size_t)k * D_FFN + col];
            #pragma unroll
            for (int o = 32; o > 0; o >>= 1) p += __shfl_xor(p, o, 64);
            if (lane == 0) redW[wid] = p;
            __syncthreads();
            if (t == 0) ambVal[j] = (redW[0] + redW[1]) + (redW[2] + redW[3]);
            __syncthreads();
        }
        if (t < na) {
            const double v = ambVal[t];
            const int    c = ambIdx[t];
            int r = 0;
            for (int j = 0; j < na; ++j) {
                const double vj = ambVal[j];
                if (vj > v || (vj == v && ambIdx[j] < c)) r++;
            }
            if (r < need) {
                const unsigned p = atomicAdd(&sh_fill, 1u);
                sIdx[nc + p] = c;
                sVal[nc + p] = (float)v;
            }
        }
        __syncthreads();
    }

    idxOut[(size_t)row * TOPK + t] = sIdx[t];
    gkOut[(size_t)row * TOPK + t] = sVal[t];
}

// ---------------------------------------------------------------------------
__global__ __launch_bounds__(256)
void z_fused(const int* __restrict__ idx, const float* __restrict__ gk,
             const float* __restrict__ U, __bf16* __restrict__ Zd)
{
    const int r = blockIdx.x, t = threadIdx.x;
    const int p = r * TOPK + t;
    const int c = idx[p];
    const float g = gk[p];
    const float u = U[(size_t)r * D_FFN + c];
    const float s = g / (1.0f + __expf(-g));
    Zd[(size_t)r * D_FFN + c] = (__bf16)(s * u);
}

__global__ __launch_bounds__(256)
void zero_buf(float4* __restrict__ p, int n)
{
    int i = blockIdx.x * 256 + threadIdx.x;
    const int stride = gridDim.x * 256;
    for (; i < n; i += stride) p[i] = make_float4(0.f, 0.f, 0.f, 0.f);
}

// ---------------------------------------------------------------------------
extern "C" void kernel_launch(void* const* d_in, const int* in_sizes, int n_in,
                              void* d_out, int out_size, void* d_ws, size_t ws_size,
                              hipStream_t stream)
{
    const float* x  = (const float*)d_in[0];
    const float* wg = (const float*)d_in[1];
    const float* wu = (const float*)d_in[2];
    const float* wd = (const float*)d_in[3];
    float* out = (float*)d_out;

    const size_t SZ_XB = (size_t)NTOK * D_MODEL * 2;
    const size_t SZ_WB = (size_t)D_FFN * D_MODEL * 2;
    const size_t SZ_IK = (size_t)NTOK * TOPK * 4;
    char* ws = (char*)d_ws;
    size_t off = 0;
    auto alloc = [&](size_t bytes) -> char* {
        char* p = ws + off;
        off += (bytes + 255) & ~(size_t)255;
        return p;
    };
    __bf16* x_hi  = (__bf16*)alloc(SZ_XB);
    __bf16* x_lo  = (__bf16*)alloc(SZ_XB);   // after G phase: reused as Zd block
    __bf16* wT_a  = (__bf16*)alloc(SZ_WB);   // wgT_hi, then wuT
    __bf16* wT_b  = (__bf16*)alloc(SZ_WB);   // wgT_lo, then wdT
    int*    idx   = (int*)  alloc(SZ_IK);
    float*  gk    = (float*)alloc(SZ_IK);
    const size_t fixed = off;

    int RB = 2048;
    while (RB > 256 && fixed + (size_t)RB * D_FFN * 4 > ws_size) RB >>= 1;
    float* Eblk = (float*)alloc((size_t)RB * D_FFN * 4);
    __bf16* Zdb = x_lo;
    const int NRB = NTOK / RB;

    // 1) operand conversions for the G phase
    split_convert<<<(NTOK * D_MODEL / 4 + 255) / 256, 256, 0, stream>>>(
        x, x_hi, x_lo, NTOK * D_MODEL / 4);
    transpose_bf16<true><<<dim3(D_FFN / 32, D_MODEL / 32), 256, 0, stream>>>(
        wg, wT_a, wT_b, D_MODEL, D_FFN);

    // 2) G phase per row-block: stacked-K bf16 GEMM -> exact topk (fp64 fixup)
    for (int rb = 0; rb < NRB; ++rb) {
        const size_t aoff = (size_t)rb * RB * D_MODEL;
        g256<3><<<dim3(D_FFN / 256, RB / 256), 512, 0, stream>>>(
            x_hi + aoff, x_lo + aoff, x_hi + aoff,
            wT_a, wT_a, wT_b, Eblk, D_MODEL, D_FFN);
        topk256<<<RB, 256, 0, stream>>>(
            Eblk, x + aoff, wg,
            idx + (size_t)rb * RB * TOPK, gk + (size_t)rb * RB * TOPK);
    }

    // 3) weight conversions for U/down phases
    transpose_bf16<false><<<dim3(D_FFN / 32, D_MODEL / 32), 256, 0, stream>>>(
        wu, wT_a, nullptr, D_MODEL, D_FFN);
    transpose_bf16<false><<<dim3(D_MODEL / 32, D_FFN / 32), 256, 0, stream>>>(
        wd, wT_b, nullptr, D_FFN, D_MODEL);

    // 4) U -> z scatter -> down projection, per row-block
    for (int rb = 0; rb < NRB; ++rb) {
        const size_t aoff = (size_t)rb * RB * D_MODEL;
        g256<1><<<dim3(D_FFN / 256, RB / 256), 512, 0, stream>>>(
            x_hi + aoff, nullptr, nullptr, wT_a, nullptr, nullptr,
            Eblk, D_MODEL, D_FFN);
        zero_buf<<<2048, 256, 0, stream>>>((float4*)Zdb, RB * (D_FFN * 2 / 16));
        z_fused<<<RB, 256, 0, stream>>>(
            idx + (size_t)rb * RB * TOPK, gk + (size_t)rb * RB * TOPK, Eblk, Zdb);
        gemm_bt<1><<<dim3(D_MODEL / 128, RB / 128), 256, 0, stream>>>(
            Zdb, nullptr, nullptr, wT_b, nullptr, nullptr,
            out + (size_t)rb * RB * D_MODEL, D_FFN, D_MODEL);
    }
}

// Round 8
// 2280.533 us; speedup vs baseline: 1.1632x; 1.1632x over previous
//
#include <hip/hip_runtime.h>
#include <hip/hip_bf16.h>
#include <stdint.h>

#define D_MODEL 2048
#define D_FFN   8192
#define NTOK    8192
#define TOPK    256

typedef __bf16 bf16x8 __attribute__((ext_vector_type(8)));
typedef __bf16 bf16x4 __attribute__((ext_vector_type(4)));
typedef float  f32x4  __attribute__((ext_vector_type(4)));

// ---------------------------------------------------------------------------
// global -> LDS direct (16B per lane; LDS dest = wave-uniform base + lane*16)
// ---------------------------------------------------------------------------
__device__ inline void load_lds16(const void* g, void* l) {
    __builtin_amdgcn_global_load_lds((__attribute__((address_space(1))) void*)g,
                                     (__attribute__((address_space(3))) void*)l,
                                     16, 0, 0);
}

// ===========================================================================
// 256x256 bf16 GEMM — faithful m201 8-phase schedule with K-half slot ring.
//   LDS: sA/sB = 4 slots x [256 rows][32 K-cols] (64 KiB each, 128 KiB total)
//   slot(J) = J & 3 for global K-half index J (K-half = 32 cols)
//   iteration i reads J = 4i..4i+3 (phases P0..P7: slot p>>1, C-half p&1)
//   staging: one operand K-half per phase: P0:A(4i+3) P1:B(4i+3) P2:A(4i+4)
//     P3:B(4i+4) P4:A(4i+5) P5:B(4i+5) P6:A(4i+6) P7:B(4i+6)
//     -> every stage lands 6 phases before its first read
//   waits: vmcnt(4) at close of P3 and P7 (vmcnt(0) on last iteration);
//     in-order vmcnt retirement => each wait retires exactly the two slots
//     read in the next 4 phases. Write-safety: slot restaged one
//     barrier-separated phase-pair after its last read (reads lgkm-drained
//     before that phase's MFMA).
//   B fragments register-reused across the C-half pair (4 ds_read phases, 8
//     on B-phases) — matches template "4 or 8 x ds_read_b128".
//   Swizzle (rule 21, both sides): global source chunk cg = cl ^ ((r>>1)&3),
//     read chunk = q ^ ((fr>>1)&3) — per-lane constants.
//   Register budget: amdgpu_waves_per_eu(2) => 256 regs/wave (r4/r5 lesson:
//     anything less spills the 128-reg accumulator to scratch).
// ===========================================================================
template<int NSEG, int SEGK, int LDC>
__global__ __attribute__((amdgpu_flat_work_group_size(512, 512),
                          amdgpu_waves_per_eu(2)))
void g256p(const __bf16* __restrict__ A0, const __bf16* __restrict__ A1,
           const __bf16* __restrict__ A2,
           const __bf16* __restrict__ B0, const __bf16* __restrict__ B1,
           const __bf16* __restrict__ B2,
           float* __restrict__ C)
{
    constexpr int NH  = NSEG * SEGK / 32;   // total K-halves
    constexpr int NIT = NH / 4;             // iterations (4 K-halves each)

    __shared__ __align__(16) __bf16 sA[4][256][32];   // 64 KiB
    __shared__ __align__(16) __bf16 sB[4][256][32];   // 64 KiB

    const int tid  = threadIdx.x;
    const int lane = tid & 63;
    const int wid  = tid >> 6;            // 0..7
    const int mb   = blockIdx.y;
    const int nb   = blockIdx.x;

    const int wm = (wid >> 2) * 128;      // wave A-rows [wm, wm+128)
    const int wn = (wid & 3) * 64;        // wave B-rows [wn, wn+64)
    const int fr = lane & 15;
    const int q  = lane >> 4;             // 0..3

    // per-lane constant swizzles
    const int swz8 = ((q ^ ((fr >> 1) & 3)) * 8);        // read chunk (elems)
    const int cl   = lane & 3;
    const int sr0  = wid * 32 + (lane >> 2);             // staging row, pass 0
    const int cg8a = (cl ^ ((sr0 >> 1) & 3)) * 8;        // src chunk pass 0/1
    // pass1 row = sr0+16 -> (r>>1)&3 unchanged (16>>1=8 ≡ 0 mod 4)

    f32x4 acc[8][4] = {};

    auto STAGE = [&](int op, int J) {
        const int s = J & 3;
        int seg = 0, kin = J * 32;
        if (NSEG > 1) { seg = (J * 32) / SEGK; kin = J * 32 - seg * SEGK; }
        const __bf16* base = op
            ? ((NSEG == 1 || seg == 0) ? B0 : (seg == 1 ? B1 : B2))
            : ((NSEG == 1 || seg == 0) ? A0 : (seg == 1 ? A1 : A2));
        const int rowbase = (op ? nb : mb) * 256;
        char* ldsb = (char*)(op ? &sB[s][0][0] : &sA[s][0][0]) + wid * 2048;
        #pragma unroll
        for (int p = 0; p < 2; ++p) {
            const int r = sr0 + p * 16;
            load_lds16(base + (size_t)(rowbase + r) * SEGK + kin + cg8a,
                       ldsb + p * 1024);
        }
    };

#define P_READ_B(s) { _Pragma("unroll") for (int ni = 0; ni < 4; ++ni) {       \
        const int r = wn + fr + ni * 16;                                       \
        bfr[ni] = *(const bf16x8*)&sB[s][r][swz8]; } }
#define P_READ_A(s, h) { _Pragma("unroll") for (int mi = 0; mi < 4; ++mi) {    \
        const int r = wm + (h) * 64 + fr + mi * 16;                            \
        af[mi] = *(const bf16x8*)&sA[s][r][swz8]; } }
#define P_MFMA(h) { __builtin_amdgcn_s_setprio(1);                             \
    _Pragma("unroll") for (int mi = 0; mi < 4; ++mi)                           \
    _Pragma("unroll") for (int ni = 0; ni < 4; ++ni)                           \
        acc[(h) * 4 + mi][ni] = __builtin_amdgcn_mfma_f32_16x16x32_bf16(       \
            af[mi], bfr[ni], acc[(h) * 4 + mi][ni], 0, 0, 0);                  \
    __builtin_amdgcn_s_setprio(0); }
#define P_STAGE(op, Joff) { const int J = J0 + (Joff);                         \
        if (J >= 4 && J < NH) STAGE(op, J); }
#define P_BAR  __builtin_amdgcn_s_barrier()
#define P_LGKM { asm volatile("s_waitcnt lgkmcnt(0)" ::: "memory");            \
                 __builtin_amdgcn_sched_barrier(0); }

    // prologue: stage slots 0..3 (J=0..3), drain, barrier
    #pragma unroll
    for (int J = 0; J < 4; ++J) { STAGE(0, J); STAGE(1, J); }
    asm volatile("s_waitcnt vmcnt(0)" ::: "memory");
    P_BAR;

    for (int i = 0; i < NIT; ++i) {
        const int J0 = 4 * i;
        const bool last = (i == NIT - 1);
        bf16x8 af[4], bfr[4];

        // P0: slot0 h0
        P_READ_B(0); P_READ_A(0, 0); P_STAGE(0, 3);
        P_BAR; P_LGKM; P_MFMA(0); P_BAR;
        // P1: slot0 h1
        P_READ_A(0, 1); P_STAGE(1, 3);
        P_BAR; P_LGKM; P_MFMA(1); P_BAR;
        // P2: slot1 h0
        P_READ_B(1); P_READ_A(1, 0); P_STAGE(0, 4);
        P_BAR; P_LGKM; P_MFMA(0); P_BAR;
        // P3: slot1 h1  (+ counted vmcnt at close)
        P_READ_A(1, 1); P_STAGE(1, 4);
        P_BAR; P_LGKM; P_MFMA(1);
        if (last) { asm volatile("s_waitcnt vmcnt(0)" ::: "memory"); }
        else      { asm volatile("s_waitcnt vmcnt(4)" ::: "memory"); }
        P_BAR;
        // P4: slot2 h0
        P_READ_B(2); P_READ_A(2, 0); P_STAGE(0, 5);
        P_BAR; P_LGKM; P_MFMA(0); P_BAR;
        // P5: slot2 h1
        P_READ_A(2, 1); P_STAGE(1, 5);
        P_BAR; P_LGKM; P_MFMA(1); P_BAR;
        // P6: slot3 h0
        P_READ_B(3); P_READ_A(3, 0); P_STAGE(0, 6);
        P_BAR; P_LGKM; P_MFMA(0); P_BAR;
        // P7: slot3 h1  (+ counted vmcnt at close)
        P_READ_A(3, 1); P_STAGE(1, 6);
        P_BAR; P_LGKM; P_MFMA(1);
        if (last) { asm volatile("s_waitcnt vmcnt(0)" ::: "memory"); }
        else      { asm volatile("s_waitcnt vmcnt(4)" ::: "memory"); }
        P_BAR;
    }

#undef P_READ_B
#undef P_READ_A
#undef P_MFMA
#undef P_STAGE
#undef P_BAR
#undef P_LGKM

    // epilogue: C/D layout col = lane&15, row = (lane>>4)*4 + reg
    const int orow = q * 4;
    #pragma unroll
    for (int ai = 0; ai < 8; ++ai) {
        const int rl = wm + (ai >> 2) * 64 + (ai & 3) * 16 + orow;
        #pragma unroll
        for (int ni = 0; ni < 4; ++ni)
            #pragma unroll
            for (int j = 0; j < 4; ++j) {
                const int r = mb * 256 + rl + j;
                const int c = nb * 256 + wn + ni * 16 + fr;
                C[(size_t)r * LDC + c] = acc[ai][ni][j];
            }
    }
}

// ---------------------------------------------------------------------------
// legacy 128x128 bf16 GEMM (m97 structure) — used for the down projection
// ---------------------------------------------------------------------------
template<int NSEG>
__global__ __launch_bounds__(256)
void gemm_bt(const __bf16* __restrict__ A0, const __bf16* __restrict__ A1,
             const __bf16* __restrict__ A2,
             const __bf16* __restrict__ B0, const __bf16* __restrict__ B1,
             const __bf16* __restrict__ B2,
             float* __restrict__ C, int segK, int ldc)
{
    __shared__ __align__(16) __bf16 sA[128][64];
    __shared__ __align__(16) __bf16 sB[128][64];

    const int tid  = threadIdx.x;
    const int lane = tid & 63;
    const int wid  = tid >> 6;
    const int mb   = blockIdx.y;
    const int nb   = blockIdx.x;

    f32x4 acc[4][4] = {};

    const int stR = wid * 8 + (lane >> 3);
    const int stC = (lane & 7) * 8;
    const int NKT = (NSEG * segK) / 64;

    for (int kt = 0; kt < NKT; ++kt) {
        const int kg  = kt * 64;
        const int seg = kg / segK;
        const int kin = kg - seg * segK;
        const __bf16* Aseg = (NSEG == 1 || seg == 0) ? A0 : (seg == 1 ? A1 : A2);
        const __bf16* Bseg = (NSEG == 1 || seg == 0) ? B0 : (seg == 1 ? B1 : B2);

        #pragma unroll
        for (int i = 0; i < 4; ++i) {
            const __bf16* gA = Aseg + (size_t)(mb * 128 + i * 32 + stR) * segK + (kin + stC);
            const __bf16* gB = Bseg + (size_t)(nb * 128 + i * 32 + stR) * segK + (kin + stC);
            load_lds16(gA, &sA[i * 32 + wid * 8][0]);
            load_lds16(gB, &sB[i * 32 + wid * 8][0]);
        }
        __syncthreads();

        const int wm = (wid >> 1) * 64;
        const int wn = (wid & 1) * 64;
        const int fr = lane & 15;
        const int fk = (lane >> 4) * 8;
        #pragma unroll
        for (int kk = 0; kk < 2; ++kk) {
            bf16x8 af[4], bfr[4];
            #pragma unroll
            for (int mi = 0; mi < 4; ++mi)
                af[mi] = *(const bf16x8*)&sA[wm + mi * 16 + fr][kk * 32 + fk];
            #pragma unroll
            for (int ni = 0; ni < 4; ++ni)
                bfr[ni] = *(const bf16x8*)&sB[wn + ni * 16 + fr][kk * 32 + fk];
            #pragma unroll
            for (int mi = 0; mi < 4; ++mi)
                #pragma unroll
                for (int ni = 0; ni < 4; ++ni)
                    acc[mi][ni] = __builtin_amdgcn_mfma_f32_16x16x32_bf16(
                        af[mi], bfr[ni], acc[mi][ni], 0, 0, 0);
        }
        __syncthreads();
    }

    const int wm = (wid >> 1) * 64;
    const int wn = (wid & 1) * 64;
    const int orow = (lane >> 4) * 4;
    const int ocol = lane & 15;
    #pragma unroll
    for (int mi = 0; mi < 4; ++mi)
        #pragma unroll
        for (int ni = 0; ni < 4; ++ni)
            #pragma unroll
            for (int j = 0; j < 4; ++j) {
                const int r = mb * 128 + wm + mi * 16 + orow + j;
                const int c = nb * 128 + wn + ni * 16 + ocol;
                C[(size_t)r * ldc + c] = acc[mi][ni][j];
            }
}

// ---------------------------------------------------------------------------
__global__ __launch_bounds__(256)
void split_convert(const float* __restrict__ in, __bf16* __restrict__ hi,
                   __bf16* __restrict__ lo, int n4)
{
    const int i = blockIdx.x * 256 + threadIdx.x;
    if (i >= n4) return;
    const float4 v = ((const float4*)in)[i];
    float f[4] = {v.x, v.y, v.z, v.w};
    bf16x4 h, l;
    #pragma unroll
    for (int j = 0; j < 4; ++j) {
        __bf16 hb = (__bf16)f[j];
        h[j] = hb;
        l[j] = (__bf16)(f[j] - (float)hb);
    }
    ((bf16x4*)hi)[i] = h;
    ((bf16x4*)lo)[i] = l;
}

// ---------------------------------------------------------------------------
template<bool SPLIT>
__global__ __launch_bounds__(256)
void transpose_bf16(const float* __restrict__ in, __bf16* __restrict__ outHi,
                    __bf16* __restrict__ outLo, int R, int C)
{
    __shared__ float tile[32][33];
    const int bx = blockIdx.x * 32;
    const int by = blockIdx.y * 32;
    const int tx = threadIdx.x & 31;
    const int ty = threadIdx.x >> 5;
    #pragma unroll
    for (int i = 0; i < 4; ++i)
        tile[ty + 8 * i][tx] = in[(size_t)(by + ty + 8 * i) * C + (bx + tx)];
    __syncthreads();
    #pragma unroll
    for (int i = 0; i < 4; ++i) {
        const float v = tile[tx][ty + 8 * i];
        const size_t o = (size_t)(bx + ty + 8 * i) * R + (by + tx);
        const __bf16 h = (__bf16)v;
        outHi[o] = h;
        if (SPLIT) outLo[o] = (__bf16)(v - (float)h);
    }
}

// ---------------------------------------------------------------------------
// exact top-256 per row of G[rows][D_FFN] fp32 (G computed to ~1e-6):
// radix-select pivot, then fp64-exact arbitration of the ambiguous boundary.
// ---------------------------------------------------------------------------
#define TK_EPS 3e-5f
#define TK_MAXA 64

__global__ __launch_bounds__(256)
void topk256(const float* __restrict__ G, const float* __restrict__ xblk,
             const float* __restrict__ wgate,
             int* __restrict__ idxOut, float* __restrict__ gkOut)
{
    const int row = blockIdx.x;
    const int t = threadIdx.x;
    const int lane = t & 63;
    const int wid  = t >> 6;

    __shared__ unsigned keys[D_FFN];
    __shared__ float    xr[D_MODEL];
    __shared__ unsigned hist[256];
    __shared__ unsigned scanb[256];
    __shared__ int      sIdx[TOPK];
    __shared__ float    sVal[TOPK];
    __shared__ int      ambIdx[TK_MAXA];
    __shared__ double   ambVal[TK_MAXA];
    __shared__ double   redW[4];
    __shared__ unsigned sh_bin, sh_above, sh_nc, sh_na, sh_fill;

    const float* g = G + (size_t)row * D_FFN;
    const float* xrow = xblk + (size_t)row * D_MODEL;
    for (int i = t; i < D_FFN; i += 256) {
        const unsigned u = __float_as_uint(g[i]);
        keys[i] = (u & 0x80000000u) ? ~u : (u | 0x80000000u);
    }
    for (int i = t; i < D_MODEL; i += 256) xr[i] = xrow[i];
    if (t == 0) { sh_nc = 0; sh_na = 0; sh_fill = 0; }
    __syncthreads();

    unsigned prefix = 0, pmask = 0;
    int remaining = TOPK;
    for (int shift = 24; shift >= 0; shift -= 8) {
        hist[t] = 0;
        __syncthreads();
        for (int i = t; i < D_FFN; i += 256) {
            const unsigned k = keys[i];
            if ((k & pmask) == prefix) atomicAdd(&hist[(k >> shift) & 255u], 1u);
        }
        __syncthreads();
        scanb[t] = hist[t];
        __syncthreads();
        for (int off = 1; off < 256; off <<= 1) {
            const unsigned add = (t + off < 256) ? scanb[t + off] : 0u;
            __syncthreads();
            scanb[t] += add;
            __syncthreads();
        }
        const unsigned above = (t == 255) ? 0u : scanb[t + 1];
        if (scanb[t] >= (unsigned)remaining && above < (unsigned)remaining) {
            sh_bin = (unsigned)t;
            sh_above = above;
        }
        __syncthreads();
        prefix |= sh_bin << shift;
        pmask  |= 0xFFu << shift;
        remaining -= (int)sh_above;
        __syncthreads();
    }
    const unsigned Tkey = prefix;
    const float vT = __uint_as_float((Tkey & 0x80000000u) ? (Tkey & 0x7FFFFFFFu) : ~Tkey);

    for (int i = t; i < D_FFN; i += 256) {
        const unsigned k = keys[i];
        const float f = __uint_as_float((k & 0x80000000u) ? (k & 0x7FFFFFFFu) : ~k);
        if (f > vT + TK_EPS) {
            const unsigned p = atomicAdd(&sh_nc, 1u);
            sIdx[p] = i;
            sVal[p] = f;
        } else if (f >= vT - TK_EPS) {
            const unsigned p = atomicAdd(&sh_na, 1u);
            if (p < TK_MAXA) ambIdx[p] = i;
        }
    }
    __syncthreads();
    const int nc = (int)sh_nc;
    const int na = min((int)sh_na, TK_MAXA);
    const int need = TOPK - nc;

    if (need >= na) {
        if (t < na) {
            const unsigned k = keys[ambIdx[t]];
            sIdx[nc + t] = ambIdx[t];
            sVal[nc + t] = __uint_as_float((k & 0x80000000u) ? (k & 0x7FFFFFFFu) : ~k);
        }
        __syncthreads();
    } else {
        for (int j = 0; j < na; ++j) {
            const int col = ambIdx[j];
            double p = 0.0;
            for (int k = t; k < D_MODEL; k += 256)
                p += (double)xr[k] * (double)wgate[(size_t)k * D_FFN + col];
            #pragma unroll
            for (int o = 32; o > 0; o >>= 1) p += __shfl_xor(p, o, 64);
            if (lane == 0) redW[wid] = p;
            __syncthreads();
            if (t == 0) ambVal[j] = (redW[0] + redW[1]) + (redW[2] + redW[3]);
            __syncthreads();
        }
        if (t < na) {
            const double v = ambVal[t];
            const int    c = ambIdx[t];
            int r = 0;
            for (int j = 0; j < na; ++j) {
                const double vj = ambVal[j];
                if (vj > v || (vj == v && ambIdx[j] < c)) r++;
            }
            if (r < need) {
                const unsigned p = atomicAdd(&sh_fill, 1u);
                sIdx[nc + p] = c;
                sVal[nc + p] = (float)v;
            }
        }
        __syncthreads();
    }

    idxOut[(size_t)row * TOPK + t] = sIdx[t];
    gkOut[(size_t)row * TOPK + t] = sVal[t];
}

// ---------------------------------------------------------------------------
__global__ __launch_bounds__(256)
void z_fused(const int* __restrict__ idx, const float* __restrict__ gk,
             const float* __restrict__ U, __bf16* __restrict__ Zd)
{
    const int r = blockIdx.x, t = threadIdx.x;
    const int p = r * TOPK + t;
    const int c = idx[p];
    const float g = gk[p];
    const float u = U[(size_t)r * D_FFN + c];
    const float s = g / (1.0f + __expf(-g));
    Zd[(size_t)r * D_FFN + c] = (__bf16)(s * u);
}

__global__ __launch_bounds__(256)
void zero_buf(float4* __restrict__ p, int n)
{
    int i = blockIdx.x * 256 + threadIdx.x;
    const int stride = gridDim.x * 256;
    for (; i < n; i += stride) p[i] = make_float4(0.f, 0.f, 0.f, 0.f);
}

// ---------------------------------------------------------------------------
extern "C" void kernel_launch(void* const* d_in, const int* in_sizes, int n_in,
                              void* d_out, int out_size, void* d_ws, size_t ws_size,
                              hipStream_t stream)
{
    const float* x  = (const float*)d_in[0];
    const float* wg = (const float*)d_in[1];
    const float* wu = (const float*)d_in[2];
    const float* wd = (const float*)d_in[3];
    float* out = (float*)d_out;

    const size_t SZ_XB = (size_t)NTOK * D_MODEL * 2;
    const size_t SZ_WB = (size_t)D_FFN * D_MODEL * 2;
    const size_t SZ_IK = (size_t)NTOK * TOPK * 4;
    char* ws = (char*)d_ws;
    size_t off = 0;
    auto alloc = [&](size_t bytes) -> char* {
        char* p = ws + off;
        off += (bytes + 255) & ~(size_t)255;
        return p;
    };
    __bf16* x_hi  = (__bf16*)alloc(SZ_XB);
    __bf16* x_lo  = (__bf16*)alloc(SZ_XB);   // after G phase: reused as Zd block
    __bf16* wT_a  = (__bf16*)alloc(SZ_WB);   // wgT_hi, then wuT
    __bf16* wT_b  = (__bf16*)alloc(SZ_WB);   // wgT_lo, then wdT
    int*    idx   = (int*)  alloc(SZ_IK);
    float*  gk    = (float*)alloc(SZ_IK);
    const size_t fixed = off;

    int RB = 2048;
    while (RB > 256 && fixed + (size_t)RB * D_FFN * 4 > ws_size) RB >>= 1;
    float* Eblk = (float*)alloc((size_t)RB * D_FFN * 4);
    __bf16* Zdb = x_lo;
    const int NRB = NTOK / RB;

    // 1) operand conversions for the G phase
    split_convert<<<(NTOK * D_MODEL / 4 + 255) / 256, 256, 0, stream>>>(
        x, x_hi, x_lo, NTOK * D_MODEL / 4);
    transpose_bf16<true><<<dim3(D_FFN / 32, D_MODEL / 32), 256, 0, stream>>>(
        wg, wT_a, wT_b, D_MODEL, D_FFN);

    // 2) G phase per row-block: stacked-K bf16 GEMM -> exact topk (fp64 fixup)
    for (int rb = 0; rb < NRB; ++rb) {
        const size_t aoff = (size_t)rb * RB * D_MODEL;
        g256p<3, D_MODEL, D_FFN><<<dim3(D_FFN / 256, RB / 256), 512, 0, stream>>>(
            x_hi + aoff, x_lo + aoff, x_hi + aoff,
            wT_a, wT_a, wT_b, Eblk);
        topk256<<<RB, 256, 0, stream>>>(
            Eblk, x + aoff, wg,
            idx + (size_t)rb * RB * TOPK, gk + (size_t)rb * RB * TOPK);
    }

    // 3) weight conversions for U/down phases
    transpose_bf16<false><<<dim3(D_FFN / 32, D_MODEL / 32), 256, 0, stream>>>(
        wu, wT_a, nullptr, D_MODEL, D_FFN);
    transpose_bf16<false><<<dim3(D_MODEL / 32, D_FFN / 32), 256, 0, stream>>>(
        wd, wT_b, nullptr, D_FFN, D_MODEL);

    // 4) U -> z scatter -> down projection, per row-block
    for (int rb = 0; rb < NRB; ++rb) {
        const size_t aoff = (size_t)rb * RB * D_MODEL;
        g256p<1, D_MODEL, D_FFN><<<dim3(D_FFN / 256, RB / 256), 512, 0, stream>>>(
            x_hi + aoff, nullptr, nullptr, wT_a, nullptr, nullptr, Eblk);
        zero_buf<<<2048, 256, 0, stream>>>((float4*)Zdb, RB * (D_FFN * 2 / 16));
        z_fused<<<RB, 256, 0, stream>>>(
            idx + (size_t)rb * RB * TOPK, gk + (size_t)rb * RB * TOPK, Eblk, Zdb);
        gemm_bt<1><<<dim3(D_MODEL / 128, RB / 128), 256, 0, stream>>>(
            Zdb, nullptr, nullptr, wT_b, nullptr, nullptr,
            out + (size_t)rb * RB * D_MODEL, D_FFN, D_MODEL);
    }
}

// Round 9
// 2249.988 us; speedup vs baseline: 1.1790x; 1.0136x over previous
//
#include <hip/hip_runtime.h>
#include <hip/hip_bf16.h>
#include <stdint.h>

#define D_MODEL 2048
#define D_FFN   8192
#define NTOK    8192
#define TOPK    256

typedef __bf16 bf16x8 __attribute__((ext_vector_type(8)));
typedef __bf16 bf16x4 __attribute__((ext_vector_type(4)));
typedef float  f32x4  __attribute__((ext_vector_type(4)));

// ---------------------------------------------------------------------------
// global -> LDS direct (16B per lane; LDS dest = wave-uniform base + lane*16)
// ---------------------------------------------------------------------------
__device__ inline void load_lds16(const void* g, void* l) {
    __builtin_amdgcn_global_load_lds((__attribute__((address_space(1))) void*)g,
                                     (__attribute__((address_space(3))) void*)l,
                                     16, 0, 0);
}

// ===========================================================================
// 256x256 bf16 GEMM — K-half slot ring, 4 merged slot-phases per iteration.
//   LDS: sA/sB = 4 slots x [256 rows][32 K-cols] (64 KiB each, 128 KiB total)
//   slot(J) = J & 3 for global K-half index J; iteration i reads J=4i..4i+3.
//   Slot-phase sp (sp=0..3): {read B(slot)+A(slot,h0); stage A&B(J0+3+sp);
//     BAR; lgkm(0); 16 MFMA h0; read A(slot,h1); lgkm(0); 16 MFMA h1;
//     [vmcnt at sp=1,3]; BAR}  -> 8 barriers/iter (was 16 in the r7/r8 form).
//   vmcnt ledger (loads; STAGE op = 2 loads, 4/slot-phase):
//     steady: p1-close 12 outstanding -> vmcnt(4) retires J0+2,J0+3 staging
//     (read at p2,p3 after the BAR); p3-close 12 -> vmcnt(4) retires
//     J0+4,J0+5 (read next iter p0,p1). Last iter: vmcnt(0) at p1 AND p3
//     (fixes r8's latent last-iter race where slot3 staging was read
//     before any vmcnt retired it).
//   Write-safety: stage(sigma) in phase p issued after phase p-1's closing
//     BAR; sigma's readers lgkm-drained before their MFMA, which precedes
//     that BAR. Mid-phase A(h1) read into the SAME af regs (register budget:
//     252/256 used; sched_barrier(0) after h0-MFMA prevents the compiler
//     from hoisting h1 reads into extra regs -> spill).
//   Register budget: amdgpu_waves_per_eu(2) => 256 regs/wave (r4/r5 lesson:
//     anything less spills the 128-reg accumulator -> 3.8 GB scratch).
// ===========================================================================
template<int NSEG, int SEGK, int LDC>
__global__ __attribute__((amdgpu_flat_work_group_size(512, 512),
                          amdgpu_waves_per_eu(2)))
void g256p(const __bf16* __restrict__ A0, const __bf16* __restrict__ A1,
           const __bf16* __restrict__ A2,
           const __bf16* __restrict__ B0, const __bf16* __restrict__ B1,
           const __bf16* __restrict__ B2,
           float* __restrict__ C)
{
    constexpr int NH  = NSEG * SEGK / 32;   // total K-halves
    constexpr int NIT = NH / 4;             // iterations (4 K-halves each)

    __shared__ __align__(16) __bf16 sA[4][256][32];   // 64 KiB
    __shared__ __align__(16) __bf16 sB[4][256][32];   // 64 KiB

    const int tid  = threadIdx.x;
    const int lane = tid & 63;
    const int wid  = tid >> 6;            // 0..7
    const int mb   = blockIdx.y;
    const int nb   = blockIdx.x;

    const int wm = (wid >> 2) * 128;      // wave A-rows [wm, wm+128)
    const int wn = (wid & 3) * 64;        // wave B-rows [wn, wn+64)
    const int fr = lane & 15;
    const int q  = lane >> 4;             // 0..3

    // per-lane constant swizzles (rule 21: same XOR on source and read)
    const int swz8 = ((q ^ ((fr >> 1) & 3)) * 8);        // read chunk (elems)
    const int cl   = lane & 3;
    const int sr0  = wid * 32 + (lane >> 2);             // staging row, pass 0
    const int cg8a = (cl ^ ((sr0 >> 1) & 3)) * 8;        // src chunk (both passes)

    f32x4 acc[8][4] = {};

    auto STAGE = [&](int op, int J) {
        const int s = J & 3;
        int seg = 0, kin = J * 32;
        if (NSEG > 1) { seg = (J * 32) / SEGK; kin = J * 32 - seg * SEGK; }
        const __bf16* base = op
            ? ((NSEG == 1 || seg == 0) ? B0 : (seg == 1 ? B1 : B2))
            : ((NSEG == 1 || seg == 0) ? A0 : (seg == 1 ? A1 : A2));
        const int rowbase = (op ? nb : mb) * 256;
        char* ldsb = (char*)(op ? &sB[s][0][0] : &sA[s][0][0]) + wid * 2048;
        #pragma unroll
        for (int p = 0; p < 2; ++p) {
            const int r = sr0 + p * 16;
            load_lds16(base + (size_t)(rowbase + r) * SEGK + kin + cg8a,
                       ldsb + p * 1024);
        }
    };

#define P_READ_B(s) { _Pragma("unroll") for (int ni = 0; ni < 4; ++ni) {       \
        const int r = wn + fr + ni * 16;                                       \
        bfr[ni] = *(const bf16x8*)&sB[s][r][swz8]; } }
#define P_READ_A(s, h) { _Pragma("unroll") for (int mi = 0; mi < 4; ++mi) {    \
        const int r = wm + (h) * 64 + fr + mi * 16;                            \
        af[mi] = *(const bf16x8*)&sA[s][r][swz8]; } }
#define P_MFMA(h) { __builtin_amdgcn_s_setprio(1);                             \
    _Pragma("unroll") for (int mi = 0; mi < 4; ++mi)                           \
    _Pragma("unroll") for (int ni = 0; ni < 4; ++ni)                           \
        acc[(h) * 4 + mi][ni] = __builtin_amdgcn_mfma_f32_16x16x32_bf16(       \
            af[mi], bfr[ni], acc[(h) * 4 + mi][ni], 0, 0, 0);                  \
    __builtin_amdgcn_s_setprio(0); }
#define P_STAGE2(Joff) { const int J = J0 + (Joff);                            \
        if (J >= 4 && J < NH) { STAGE(0, J); STAGE(1, J); } }
#define P_BAR  __builtin_amdgcn_s_barrier()
#define P_LGKM { asm volatile("s_waitcnt lgkmcnt(0)" ::: "memory");            \
                 __builtin_amdgcn_sched_barrier(0); }
// one merged slot-phase: sp = slot, VM = vmcnt wait (or empty)
#define SLOT_PHASE(sp, VM) {                                                   \
        P_READ_B(sp); P_READ_A(sp, 0);                                         \
        P_STAGE2(3 + (sp));                                                    \
        P_BAR; P_LGKM;                                                         \
        P_MFMA(0);                                                             \
        __builtin_amdgcn_sched_barrier(0);                                     \
        P_READ_A(sp, 1);                                                       \
        P_LGKM;                                                                \
        P_MFMA(1);                                                             \
        VM;                                                                    \
        P_BAR; }

    // prologue: stage slots 0..3 (J=0..3), drain, barrier
    #pragma unroll
    for (int J = 0; J < 4; ++J) { STAGE(0, J); STAGE(1, J); }
    asm volatile("s_waitcnt vmcnt(0)" ::: "memory");
    P_BAR;

    for (int i = 0; i < NIT; ++i) {
        const int J0 = 4 * i;
        const bool last = (i == NIT - 1);
        bf16x8 af[4], bfr[4];

        SLOT_PHASE(0, );
        SLOT_PHASE(1,
            if (last) { asm volatile("s_waitcnt vmcnt(0)" ::: "memory"); }
            else      { asm volatile("s_waitcnt vmcnt(4)" ::: "memory"); });
        SLOT_PHASE(2, );
        SLOT_PHASE(3,
            if (last) { asm volatile("s_waitcnt vmcnt(0)" ::: "memory"); }
            else      { asm volatile("s_waitcnt vmcnt(4)" ::: "memory"); });
    }

#undef P_READ_B
#undef P_READ_A
#undef P_MFMA
#undef P_STAGE2
#undef P_BAR
#undef P_LGKM
#undef SLOT_PHASE

    // epilogue: C/D layout col = lane&15, row = (lane>>4)*4 + reg
    const int orow = q * 4;
    #pragma unroll
    for (int ai = 0; ai < 8; ++ai) {
        const int rl = wm + (ai >> 2) * 64 + (ai & 3) * 16 + orow;
        #pragma unroll
        for (int ni = 0; ni < 4; ++ni)
            #pragma unroll
            for (int j = 0; j < 4; ++j) {
                const int r = mb * 256 + rl + j;
                const int c = nb * 256 + wn + ni * 16 + fr;
                C[(size_t)r * LDC + c] = acc[ai][ni][j];
            }
    }
}

// ---------------------------------------------------------------------------
// legacy 128x128 bf16 GEMM (m97 structure) — used for the down projection
// ---------------------------------------------------------------------------
template<int NSEG>
__global__ __launch_bounds__(256)
void gemm_bt(const __bf16* __restrict__ A0, const __bf16* __restrict__ A1,
             const __bf16* __restrict__ A2,
             const __bf16* __restrict__ B0, const __bf16* __restrict__ B1,
             const __bf16* __restrict__ B2,
             float* __restrict__ C, int segK, int ldc)
{
    __shared__ __align__(16) __bf16 sA[128][64];
    __shared__ __align__(16) __bf16 sB[128][64];

    const int tid  = threadIdx.x;
    const int lane = tid & 63;
    const int wid  = tid >> 6;
    const int mb   = blockIdx.y;
    const int nb   = blockIdx.x;

    f32x4 acc[4][4] = {};

    const int stR = wid * 8 + (lane >> 3);
    const int stC = (lane & 7) * 8;
    const int NKT = (NSEG * segK) / 64;

    for (int kt = 0; kt < NKT; ++kt) {
        const int kg  = kt * 64;
        const int seg = kg / segK;
        const int kin = kg - seg * segK;
        const __bf16* Aseg = (NSEG == 1 || seg == 0) ? A0 : (seg == 1 ? A1 : A2);
        const __bf16* Bseg = (NSEG == 1 || seg == 0) ? B0 : (seg == 1 ? B1 : B2);

        #pragma unroll
        for (int i = 0; i < 4; ++i) {
            const __bf16* gA = Aseg + (size_t)(mb * 128 + i * 32 + stR) * segK + (kin + stC);
            const __bf16* gB = Bseg + (size_t)(nb * 128 + i * 32 + stR) * segK + (kin + stC);
            load_lds16(gA, &sA[i * 32 + wid * 8][0]);
            load_lds16(gB, &sB[i * 32 + wid * 8][0]);
        }
        __syncthreads();

        const int wm = (wid >> 1) * 64;
        const int wn = (wid & 1) * 64;
        const int fr = lane & 15;
        const int fk = (lane >> 4) * 8;
        #pragma unroll
        for (int kk = 0; kk < 2; ++kk) {
            bf16x8 af[4], bfr[4];
            #pragma unroll
            for (int mi = 0; mi < 4; ++mi)
                af[mi] = *(const bf16x8*)&sA[wm + mi * 16 + fr][kk * 32 + fk];
            #pragma unroll
            for (int ni = 0; ni < 4; ++ni)
                bfr[ni] = *(const bf16x8*)&sB[wn + ni * 16 + fr][kk * 32 + fk];
            #pragma unroll
            for (int mi = 0; mi < 4; ++mi)
                #pragma unroll
                for (int ni = 0; ni < 4; ++ni)
                    acc[mi][ni] = __builtin_amdgcn_mfma_f32_16x16x32_bf16(
                        af[mi], bfr[ni], acc[mi][ni], 0, 0, 0);
        }
        __syncthreads();
    }

    const int wm = (wid >> 1) * 64;
    const int wn = (wid & 1) * 64;
    const int orow = (lane >> 4) * 4;
    const int ocol = lane & 15;
    #pragma unroll
    for (int mi = 0; mi < 4; ++mi)
        #pragma unroll
        for (int ni = 0; ni < 4; ++ni)
            #pragma unroll
            for (int j = 0; j < 4; ++j) {
                const int r = mb * 128 + wm + mi * 16 + orow + j;
                const int c = nb * 128 + wn + ni * 16 + ocol;
                C[(size_t)r * ldc + c] = acc[mi][ni][j];
            }
}

// ---------------------------------------------------------------------------
__global__ __launch_bounds__(256)
void split_convert(const float* __restrict__ in, __bf16* __restrict__ hi,
                   __bf16* __restrict__ lo, int n4)
{
    const int i = blockIdx.x * 256 + threadIdx.x;
    if (i >= n4) return;
    const float4 v = ((const float4*)in)[i];
    float f[4] = {v.x, v.y, v.z, v.w};
    bf16x4 h, l;
    #pragma unroll
    for (int j = 0; j < 4; ++j) {
        __bf16 hb = (__bf16)f[j];
        h[j] = hb;
        l[j] = (__bf16)(f[j] - (float)hb);
    }
    ((bf16x4*)hi)[i] = h;
    ((bf16x4*)lo)[i] = l;
}

// ---------------------------------------------------------------------------
template<bool SPLIT>
__global__ __launch_bounds__(256)
void transpose_bf16(const float* __restrict__ in, __bf16* __restrict__ outHi,
                    __bf16* __restrict__ outLo, int R, int C)
{
    __shared__ float tile[32][33];
    const int bx = blockIdx.x * 32;
    const int by = blockIdx.y * 32;
    const int tx = threadIdx.x & 31;
    const int ty = threadIdx.x >> 5;
    #pragma unroll
    for (int i = 0; i < 4; ++i)
        tile[ty + 8 * i][tx] = in[(size_t)(by + ty + 8 * i) * C + (bx + tx)];
    __syncthreads();
    #pragma unroll
    for (int i = 0; i < 4; ++i) {
        const float v = tile[tx][ty + 8 * i];
        const size_t o = (size_t)(bx + ty + 8 * i) * R + (by + tx);
        const __bf16 h = (__bf16)v;
        outHi[o] = h;
        if (SPLIT) outLo[o] = (__bf16)(v - (float)h);
    }
}

// ---------------------------------------------------------------------------
// exact top-256 per row of G[rows][D_FFN] fp32 (G computed to ~1e-6):
// radix-select pivot, then fp64-exact arbitration of the ambiguous boundary.
// ---------------------------------------------------------------------------
#define TK_EPS 3e-5f
#define TK_MAXA 64

__global__ __launch_bounds__(256)
void topk256(const float* __restrict__ G, const float* __restrict__ xblk,
             const float* __restrict__ wgate,
             int* __restrict__ idxOut, float* __restrict__ gkOut)
{
    const int row = blockIdx.x;
    const int t = threadIdx.x;
    const int lane = t & 63;
    const int wid  = t >> 6;

    __shared__ unsigned keys[D_FFN];
    __shared__ float    xr[D_MODEL];
    __shared__ unsigned hist[256];
    __shared__ unsigned scanb[256];
    __shared__ int      sIdx[TOPK];
    __shared__ float    sVal[TOPK];
    __shared__ int      ambIdx[TK_MAXA];
    __shared__ double   ambVal[TK_MAXA];
    __shared__ double   redW[4];
    __shared__ unsigned sh_bin, sh_above, sh_nc, sh_na, sh_fill;

    const float* g = G + (size_t)row * D_FFN;
    const float* xrow = xblk + (size_t)row * D_MODEL;
    for (int i = t; i < D_FFN; i += 256) {
        const unsigned u = __float_as_uint(g[i]);
        keys[i] = (u & 0x80000000u) ? ~u : (u | 0x80000000u);
    }
    for (int i = t; i < D_MODEL; i += 256) xr[i] = xrow[i];
    if (t == 0) { sh_nc = 0; sh_na = 0; sh_fill = 0; }
    __syncthreads();

    unsigned prefix = 0, pmask = 0;
    int remaining = TOPK;
    for (int shift = 24; shift >= 0; shift -= 8) {
        hist[t] = 0;
        __syncthreads();
        for (int i = t; i < D_FFN; i += 256) {
            const unsigned k = keys[i];
            if ((k & pmask) == prefix) atomicAdd(&hist[(k >> shift) & 255u], 1u);
        }
        __syncthreads();
        scanb[t] = hist[t];
        __syncthreads();
        for (int off = 1; off < 256; off <<= 1) {
            const unsigned add = (t + off < 256) ? scanb[t + off] : 0u;
            __syncthreads();
            scanb[t] += add;
            __syncthreads();
        }
        const unsigned above = (t == 255) ? 0u : scanb[t + 1];
        if (scanb[t] >= (unsigned)remaining && above < (unsigned)remaining) {
            sh_bin = (unsigned)t;
            sh_above = above;
        }
        __syncthreads();
        prefix |= sh_bin << shift;
        pmask  |= 0xFFu << shift;
        remaining -= (int)sh_above;
        __syncthreads();
    }
    const unsigned Tkey = prefix;
    const float vT = __uint_as_float((Tkey & 0x80000000u) ? (Tkey & 0x7FFFFFFFu) : ~Tkey);

    for (int i = t; i < D_FFN; i += 256) {
        const unsigned k = keys[i];
        const float f = __uint_as_float((k & 0x80000000u) ? (k & 0x7FFFFFFFu) : ~k);
        if (f > vT + TK_EPS) {
            const unsigned p = atomicAdd(&sh_nc, 1u);
            sIdx[p] = i;
            sVal[p] = f;
        } else if (f >= vT - TK_EPS) {
            const unsigned p = atomicAdd(&sh_na, 1u);
            if (p < TK_MAXA) ambIdx[p] = i;
        }
    }
    __syncthreads();
    const int nc = (int)sh_nc;
    const int na = min((int)sh_na, TK_MAXA);
    const int need = TOPK - nc;

    if (need >= na) {
        if (t < na) {
            const unsigned k = keys[ambIdx[t]];
            sIdx[nc + t] = ambIdx[t];
            sVal[nc + t] = __uint_as_float((k & 0x80000000u) ? (k & 0x7FFFFFFFu) : ~k);
        }
        __syncthreads();
    } else {
        for (int j = 0; j < na; ++j) {
            const int col = ambIdx[j];
            double p = 0.0;
            for (int k = t; k < D_MODEL; k += 256)
                p += (double)xr[k] * (double)wgate[(size_t)k * D_FFN + col];
            #pragma unroll
            for (int o = 32; o > 0; o >>= 1) p += __shfl_xor(p, o, 64);
            if (lane == 0) redW[wid] = p;
            __syncthreads();
            if (t == 0) ambVal[j] = (redW[0] + redW[1]) + (redW[2] + redW[3]);
            __syncthreads();
        }
        if (t < na) {
            const double v = ambVal[t];
            const int    c = ambIdx[t];
            int r = 0;
            for (int j = 0; j < na; ++j) {
                const double vj = ambVal[j];
                if (vj > v || (vj == v && ambIdx[j] < c)) r++;
            }
            if (r < need) {
                const unsigned p = atomicAdd(&sh_fill, 1u);
                sIdx[nc + p] = c;
                sVal[nc + p] = (float)v;
            }
        }
        __syncthreads();
    }

    idxOut[(size_t)row * TOPK + t] = sIdx[t];
    gkOut[(size_t)row * TOPK + t] = sVal[t];
}

// ---------------------------------------------------------------------------
__global__ __launch_bounds__(256)
void z_fused(const int* __restrict__ idx, const float* __restrict__ gk,
             const float* __restrict__ U, __bf16* __restrict__ Zd)
{
    const int r = blockIdx.x, t = threadIdx.x;
    const int p = r * TOPK + t;
    const int c = idx[p];
    const float g = gk[p];
    const float u = U[(size_t)r * D_FFN + c];
    const float s = g / (1.0f + __expf(-g));
    Zd[(size_t)r * D_FFN + c] = (__bf16)(s * u);
}

__global__ __launch_bounds__(256)
void zero_buf(float4* __restrict__ p, int n)
{
    int i = blockIdx.x * 256 + threadIdx.x;
    const int stride = gridDim.x * 256;
    for (; i < n; i += stride) p[i] = make_float4(0.f, 0.f, 0.f, 0.f);
}

// ---------------------------------------------------------------------------
extern "C" void kernel_launch(void* const* d_in, const int* in_sizes, int n_in,
                              void* d_out, int out_size, void* d_ws, size_t ws_size,
                              hipStream_t stream)
{
    const float* x  = (const float*)d_in[0];
    const float* wg = (const float*)d_in[1];
    const float* wu = (const float*)d_in[2];
    const float* wd = (const float*)d_in[3];
    float* out = (float*)d_out;

    const size_t SZ_XB = (size_t)NTOK * D_MODEL * 2;
    const size_t SZ_WB = (size_t)D_FFN * D_MODEL * 2;
    const size_t SZ_IK = (size_t)NTOK * TOPK * 4;
    char* ws = (char*)d_ws;
    size_t off = 0;
    auto alloc = [&](size_t bytes) -> char* {
        char* p = ws + off;
        off += (bytes + 255) & ~(size_t)255;
        return p;
    };
    __bf16* x_hi  = (__bf16*)alloc(SZ_XB);
    __bf16* x_lo  = (__bf16*)alloc(SZ_XB);   // after G phase: reused as Zd block
    __bf16* wT_a  = (__bf16*)alloc(SZ_WB);   // wgT_hi, then wuT
    __bf16* wT_b  = (__bf16*)alloc(SZ_WB);   // wgT_lo, then wdT
    int*    idx   = (int*)  alloc(SZ_IK);
    float*  gk    = (float*)alloc(SZ_IK);
    const size_t fixed = off;

    int RB = 2048;
    while (RB > 256 && fixed + (size_t)RB * D_FFN * 4 > ws_size) RB >>= 1;
    float* Eblk = (float*)alloc((size_t)RB * D_FFN * 4);
    __bf16* Zdb = x_lo;
    const int NRB = NTOK / RB;

    // 1) operand conversions for the G phase
    split_convert<<<(NTOK * D_MODEL / 4 + 255) / 256, 256, 0, stream>>>(
        x, x_hi, x_lo, NTOK * D_MODEL / 4);
    transpose_bf16<true><<<dim3(D_FFN / 32, D_MODEL / 32), 256, 0, stream>>>(
        wg, wT_a, wT_b, D_MODEL, D_FFN);

    // 2) G phase per row-block: stacked-K bf16 GEMM -> exact topk (fp64 fixup)
    for (int rb = 0; rb < NRB; ++rb) {
        const size_t aoff = (size_t)rb * RB * D_MODEL;
        g256p<3, D_MODEL, D_FFN><<<dim3(D_FFN / 256, RB / 256), 512, 0, stream>>>(
            x_hi + aoff, x_lo + aoff, x_hi + aoff,
            wT_a, wT_a, wT_b, Eblk);
        topk256<<<RB, 256, 0, stream>>>(
            Eblk, x + aoff, wg,
            idx + (size_t)rb * RB * TOPK, gk + (size_t)rb * RB * TOPK);
    }

    // 3) weight conversions for U/down phases
    transpose_bf16<false><<<dim3(D_FFN / 32, D_MODEL / 32), 256, 0, stream>>>(
        wu, wT_a, nullptr, D_MODEL, D_FFN);
    transpose_bf16<false><<<dim3(D_MODEL / 32, D_FFN / 32), 256, 0, stream>>>(
        wd, wT_b, nullptr, D_FFN, D_MODEL);

    // 4) U -> z scatter -> down projection, per row-block
    for (int rb = 0; rb < NRB; ++rb) {
        const size_t aoff = (size_t)rb * RB * D_MODEL;
        g256p<1, D_MODEL, D_FFN><<<dim3(D_FFN / 256, RB / 256), 512, 0, stream>>>(
            x_hi + aoff, nullptr, nullptr, wT_a, nullptr, nullptr, Eblk);
        zero_buf<<<2048, 256, 0, stream>>>((float4*)Zdb, RB * (D_FFN * 2 / 16));
        z_fused<<<RB, 256, 0, stream>>>(
            idx + (size_t)rb * RB * TOPK, gk + (size_t)rb * RB * TOPK, Eblk, Zdb);
        gemm_bt<1><<<dim3(D_MODEL / 128, RB / 128), 256, 0, stream>>>(
            Zdb, nullptr, nullptr, wT_b, nullptr, nullptr,
            out + (size_t)rb * RB * D_MODEL, D_FFN, D_MODEL);
    }
}